// Round 1
// baseline (858.720 us; speedup 1.0000x reference)
//
#include <hip/hip_runtime.h>
#include <hip/hip_bf16.h>
#include <hip/hip_cooperative_groups.h>

namespace cg = cooperative_groups;

// Problem constants (fixed by reference setup_inputs)
constexpr int B_   = 16384;
constexpr int L_   = 10;
constexpr int E_   = 64;
constexpr int BL_  = B_ * L_;       // 163840
constexpr int H1_  = 64;
constexpr int H2_  = 16;
constexpr int CF_  = 3 * E_;        // 192
constexpr int F1_  = 200;
constexpr int F2_  = 80;

// Workspace layout (in floats)
constexpr long OFF_SCORE = 10485760;                // BL floats (aliases W1t bf16 early)
constexpr long OFF_CF    = 10649600;                // B*192
constexpr long OFF_ACC   = 13795328;                // accumulators + wv
constexpr long OFF_Z1    = 0;                       // B*200
constexpr long OFF_Z2    = 3276800;                 // B*80
constexpr int  ACC_N     = 688;

typedef __bf16 bf16x8 __attribute__((ext_vector_type(8)));
typedef float  f32x4  __attribute__((ext_vector_type(4)));

__device__ __forceinline__ float sigmoidf_(float x) {
    return 1.0f / (1.0f + __expf(-x));
}

__device__ __forceinline__ unsigned short f2bf(float f) {
    unsigned u = __float_as_uint(f);
    unsigned r = (u + 0x7fffu + ((u >> 16) & 1u)) >> 16;   // RNE, values are finite
    return (unsigned short)r;
}
__device__ __forceinline__ unsigned pk2(float a, float b) {
    return (unsigned)f2bf(a) | ((unsigned)f2bf(b) << 16);
}

// ---------------- K0: zero accumulators, build W1t (bf16^T), fold W2@Wf -----
__global__ __launch_bounds__(256) void k_init(
    float* __restrict__ acc, const float* __restrict__ W1,
    unsigned short* __restrict__ W1t,
    const float* __restrict__ W2, const float* __restrict__ Wf,
    const float* __restrict__ b2, const float* __restrict__ bfv,
    float* __restrict__ wv)
{
    int i = blockIdx.x * 256 + threadIdx.x;   // grid 64 -> i < 16384
    if (i < ACC_N) acc[i] = 0.0f;
    if (i < 64) {
        float s = 0.0f;
        #pragma unroll
        for (int n = 0; n < 16; n++) s += W2[i * 16 + n] * Wf[n];
        wv[i] = s;                             // wv = W2 @ Wf  (64)
    } else if (i == 64) {
        float s = bfv[0];
        #pragma unroll
        for (int n = 0; n < 16; n++) s += b2[n] * Wf[n];
        wv[64] = s;                            // c0 = b2·Wf + bf
    }
    // W1 is [K=256][N=64] row-major f32; W1t is [N=64][K=256] bf16
    int k = i >> 6, n = i & 63;               // coalesced read of W1
    W1t[n * 256 + k] = f2bf(W1[i]);
}

// ---------------- K1 (cooperative): MFMA gemm1 + stats + fused dice3/score --
// Phase 1: acc = ai @ W1 + b1 kept in VGPRs (4 tiles x 64 rows per block),
//          per-column sum/ssq atomicAdd'd.  grid.sync().
// Phase 2: normalize, dice3, score = d · (W2@Wf) + c0, mask, write score.
// t1 (42 MB) never touches HBM.
constexpr int AROW = 132;   // uints per A row: 256 bf16 = 128 dwords, +4 dword pad
__global__ __launch_bounds__(256, 3) void k_gemm1(
    const int* __restrict__ sparse, const int* __restrict__ seqs,
    const float* __restrict__ item_t, const float* __restrict__ his_t,
    const unsigned short* __restrict__ W1t, const float* __restrict__ b1,
    const float* __restrict__ g1, const float* __restrict__ be1,
    const float* __restrict__ a1v, const float* __restrict__ wv,
    float* __restrict__ sum1, float* __restrict__ ssq1,
    float* __restrict__ score)
{
    __shared__ unsigned As[64 * AROW];        // 33 KB
    __shared__ float redS[4][64];
    __shared__ float redQ[4][64];

    int tid  = threadIdx.x;
    int lane = tid & 63;
    int wave = tid >> 6;
    int m    = lane & 15;
    int quad = (lane >> 4) & 3;
    int colg = 16 * wave + m;                 // this lane's output column

    // B fragments: b_frag[kk][j] = W1t[colg][kk*32 + quad*8 + j]
    bf16x8 bfr[8];
    {
        const unsigned short* wp = W1t + (long)colg * 256 + quad * 8;
        #pragma unroll
        for (int kk = 0; kk < 8; kk++)
            bfr[kk] = *(const bf16x8*)(wp + kk * 32);
    }
    float bias = b1[colg];
    float ps = 0.0f, pq = 0.0f;
    int row0base = blockIdx.x * 256;          // grid 640 -> 4 tiles of 64 rows

    f32x4 acc[4][4];                          // [tile][row-slice], 64 VGPRs

    #pragma unroll
    for (int ti = 0; ti < 4; ti++) {
        int row0 = row0base + ti * 64;
        __syncthreads();                      // As readers from prev tile done
        // stage ai tile: 64 rows x 32 bf16-pairs, 4 segments (q,h,q-h,q*h)
        #pragma unroll
        for (int t = 0; t < 8; t++) {
            int slot = t * 256 + tid;         // 0..2047
            int p = slot & 31;                // pair index (cols 2p,2p+1)
            int r = slot >> 5;                // row within tile
            int row = row0 + r;
            int b = (unsigned)row / 10u;
            int item = sparse[2 * b + 1];
            int hidx = seqs[row];
            float2 q2 = *(const float2*)(item_t + (long)item * 64 + 2 * p);
            float2 h2 = *(const float2*)(his_t  + (long)hidx * 64 + 2 * p);
            unsigned* a = &As[r * AROW];
            a[p]      = pk2(q2.x, q2.y);
            a[32 + p] = pk2(h2.x, h2.y);
            a[64 + p] = pk2(q2.x - h2.x, q2.y - h2.y);
            a[96 + p] = pk2(q2.x * h2.x, q2.y * h2.y);
        }
        __syncthreads();

        #pragma unroll
        for (int rs = 0; rs < 4; rs++) acc[ti][rs] = (f32x4){0.f, 0.f, 0.f, 0.f};
        #pragma unroll
        for (int kk = 0; kk < 8; kk++) {
            int aoff = kk * 16 + quad * 4;    // dword offset for k = kk*32 + quad*8
            bf16x8 a0 = *(const bf16x8*)&As[( 0 + m) * AROW + aoff];
            bf16x8 a1 = *(const bf16x8*)&As[(16 + m) * AROW + aoff];
            bf16x8 a2 = *(const bf16x8*)&As[(32 + m) * AROW + aoff];
            bf16x8 a3 = *(const bf16x8*)&As[(48 + m) * AROW + aoff];
            acc[ti][0] = __builtin_amdgcn_mfma_f32_16x16x32_bf16(a0, bfr[kk], acc[ti][0], 0, 0, 0);
            acc[ti][1] = __builtin_amdgcn_mfma_f32_16x16x32_bf16(a1, bfr[kk], acc[ti][1], 0, 0, 0);
            acc[ti][2] = __builtin_amdgcn_mfma_f32_16x16x32_bf16(a2, bfr[kk], acc[ti][2], 0, 0, 0);
            acc[ti][3] = __builtin_amdgcn_mfma_f32_16x16x32_bf16(a3, bfr[kk], acc[ti][3], 0, 0, 0);
        }
        // fold bias in and accumulate column stats (row = 16*rs+quad*4+reg, col = colg)
        #pragma unroll
        for (int rs = 0; rs < 4; rs++) {
            #pragma unroll
            for (int reg = 0; reg < 4; reg++) {
                float v = acc[ti][rs][reg] + bias;
                acc[ti][rs][reg] = v;
                ps += v; pq += v * v;
            }
        }
    }

    __syncthreads();
    redS[quad][colg] = ps;
    redQ[quad][colg] = pq;
    __syncthreads();
    if (tid < 64) {
        float s = redS[0][tid] + redS[1][tid] + redS[2][tid] + redS[3][tid];
        float q = redQ[0][tid] + redQ[1][tid] + redQ[2][tid] + redQ[3][tid];
        atomicAdd(&sum1[tid], s);
        atomicAdd(&ssq1[tid], q);
    }
    __threadfence();
    cg::this_grid().sync();                   // stats complete grid-wide

    // ----- phase 2: dice3 + fused (W2@Wf) dot + mask, all from registers ----
    float mu   = sum1[colg] * (1.0f / BL_);
    float var  = ssq1[colg] * (1.0f / BL_) - mu * mu;
    float rstd = rsqrtf(var + 1e-8f);
    float A  = rstd * g1[colg];
    float Bc = be1[colg] - mu * A;
    float al = a1v[colg];
    float wvc = wv[colg];
    float c0  = wv[64];

    #pragma unroll
    for (int ti = 0; ti < 4; ti++) {
        int row0 = row0base + ti * 64;
        #pragma unroll
        for (int rs = 0; rs < 4; rs++) {
            #pragma unroll
            for (int reg = 0; reg < 4; reg++) {
                float v  = acc[ti][rs][reg];
                float xn = v * A + Bc;
                float p  = sigmoidf_(xn);
                float d  = v * (al + p * (1.0f - al));
                float c  = d * wvc;
                // sum over the 16 column-lanes of this quad (cols colg..)
                c += __shfl_xor(c, 1);
                c += __shfl_xor(c, 2);
                c += __shfl_xor(c, 4);
                c += __shfl_xor(c, 8);
                if (m == 0) redS[wave][16 * rs + quad * 4 + reg] = c;
            }
        }
        __syncthreads();
        if (tid < 64) {
            int rg = row0 + tid;
            float sc = redS[0][tid] + redS[1][tid] + redS[2][tid] + redS[3][tid] + c0;
            score[rg] = (seqs[rg] == 0) ? 0.0f : sc;
        }
        __syncthreads();
    }
}

// ---------------- K2b: pooled + cf assembly ----------------------------------
__global__ __launch_bounds__(256) void k_pool(
    const int* __restrict__ sparse, const int* __restrict__ seqs,
    const float* __restrict__ user_t, const float* __restrict__ item_t,
    const float* __restrict__ his_t,
    const float* __restrict__ score, float* __restrict__ cf)
{
    int tid = threadIdx.x;
    int b = blockIdx.x * 4 + (tid >> 6);   // grid = 4096 exact
    int e = tid & 63;
    float acc = 0.0f;
    #pragma unroll
    for (int l = 0; l < L_; l++) {
        float s = score[b * L_ + l];
        int hidx = seqs[b * L_ + l];
        acc += s * his_t[(long)hidx * 64 + e];
    }
    int uidx = sparse[2 * b];
    int iidx = sparse[2 * b + 1];
    cf[(long)b * CF_ + e]        = item_t[(long)iidx * 64 + e];
    cf[(long)b * CF_ + 64 + e]   = acc;
    cf[(long)b * CF_ + 128 + e]  = user_t[(long)uidx * 64 + e];
}

// ---------------- K3: z1 = cf @ Wa + ba, plus sums ---------------------------
__global__ __launch_bounds__(256) void k_z1(
    const float* __restrict__ cf, const float* __restrict__ Wa, const float* __restrict__ ba,
    float* __restrict__ z1, float* __restrict__ sumA, float* __restrict__ ssqA)
{
    __shared__ float cfs[16 * CF_];   // 12 KB
    int tid = threadIdx.x;
    int n = tid;                      // active when n < 200
    float bav = (n < F1_) ? ba[n] : 0.0f;
    float ps = 0.f, pq = 0.f;

    int ntile = B_ / 16;   // 1024
    for (int tile = blockIdx.x; tile < ntile; tile += gridDim.x) {
        int row0 = tile * 16;
        __syncthreads();
        for (int i = tid; i < 16 * CF_; i += 256) cfs[i] = cf[(long)row0 * CF_ + i];
        __syncthreads();
        if (n < F1_) {
            float acc[16];
            #pragma unroll
            for (int r = 0; r < 16; r++) acc[r] = 0.0f;
            for (int k = 0; k < CF_; k += 4) {
                float w0 = Wa[(long)(k + 0) * F1_ + n];
                float w1 = Wa[(long)(k + 1) * F1_ + n];
                float w2 = Wa[(long)(k + 2) * F1_ + n];
                float w3 = Wa[(long)(k + 3) * F1_ + n];
                #pragma unroll
                for (int r = 0; r < 16; r++) {
                    float4 c4 = *(const float4*)&cfs[r * CF_ + k];
                    acc[r] += c4.x * w0 + c4.y * w1 + c4.z * w2 + c4.w * w3;
                }
            }
            #pragma unroll
            for (int r = 0; r < 16; r++) {
                float v = acc[r] + bav;
                z1[(long)(row0 + r) * F1_ + n] = v;
                ps += v; pq += v * v;
            }
        }
    }
    if (n < F1_) {
        atomicAdd(&sumA[n], ps);
        atomicAdd(&ssqA[n], pq);
    }
}

// ---------------- K4: z2 = dice2(z1) @ Wb + bb, plus sums --------------------
__global__ __launch_bounds__(320) void k_z2(
    const float* __restrict__ z1, const float* __restrict__ Wb, const float* __restrict__ bbv,
    const float* __restrict__ sumA, const float* __restrict__ ssqA,
    const float* __restrict__ ga, const float* __restrict__ bea, const float* __restrict__ aav,
    float* __restrict__ z2, float* __restrict__ sumB, float* __restrict__ ssqB)
{
    __shared__ float zs[16 * F1_];    // 12.8 KB
    __shared__ float Aa[F1_], Ba[F1_], ala[F1_];
    int tid = threadIdx.x;
    if (tid < F1_) {
        float mu = sumA[tid] * (1.0f / B_);
        float var = ssqA[tid] * (1.0f / B_) - mu * mu;
        float rstd = rsqrtf(var + 1e-8f);
        float A = rstd * ga[tid];
        Aa[tid] = A;
        Ba[tid] = bea[tid] - mu * A;
        ala[tid] = aav[tid];
    }
    int n = tid % F2_;       // 0..79
    int rgrp = tid / F2_;    // 0..3
    float bbl = bbv[n];
    float ps = 0.f, pq = 0.f;

    int ntile = B_ / 16;   // 1024
    for (int tile = blockIdx.x; tile < ntile; tile += gridDim.x) {
        int row0 = tile * 16;
        __syncthreads();
        for (int i = tid; i < 16 * F1_; i += 320) {
            int k = i % F1_;
            float x = z1[(long)row0 * F1_ + i];
            float xn = x * Aa[k] + Ba[k];
            float p = sigmoidf_(xn);
            float al = ala[k];
            zs[i] = x * (al + p * (1.0f - al));
        }
        __syncthreads();
        float acc[4] = {0.f, 0.f, 0.f, 0.f};
        for (int k = 0; k < F1_; k += 4) {
            float w0 = Wb[(long)(k + 0) * F2_ + n];
            float w1 = Wb[(long)(k + 1) * F2_ + n];
            float w2 = Wb[(long)(k + 2) * F2_ + n];
            float w3 = Wb[(long)(k + 3) * F2_ + n];
            #pragma unroll
            for (int rr = 0; rr < 4; rr++) {
                float4 c4 = *(const float4*)&zs[(rgrp * 4 + rr) * F1_ + k];
                acc[rr] += c4.x * w0 + c4.y * w1 + c4.z * w2 + c4.w * w3;
            }
        }
        #pragma unroll
        for (int rr = 0; rr < 4; rr++) {
            int row = row0 + rgrp * 4 + rr;
            float v = acc[rr] + bbl;
            z2[(long)row * F2_ + n] = v;
            ps += v; pq += v * v;
        }
    }
    atomicAdd(&sumB[n], ps);
    atomicAdd(&ssqB[n], pq);
}

// ---------------- K5: out = sigmoid(dice2(z2) @ Wc + bc) ---------------------
__global__ __launch_bounds__(256) void k_out(
    const float* __restrict__ z2,
    const float* __restrict__ sumB, const float* __restrict__ ssqB,
    const float* __restrict__ gb, const float* __restrict__ beb, const float* __restrict__ abv,
    const float* __restrict__ Wc, const float* __restrict__ bc,
    float* __restrict__ out)
{
    __shared__ float Ab[F2_], Bb[F2_], alb[F2_], Wcs[F2_];
    int tid = threadIdx.x;
    if (tid < F2_) {
        float mu = sumB[tid] * (1.0f / B_);
        float var = ssqB[tid] * (1.0f / B_) - mu * mu;
        float rstd = rsqrtf(var + 1e-8f);
        float A = rstd * gb[tid];
        Ab[tid] = A;
        Bb[tid] = beb[tid] - mu * A;
        alb[tid] = abv[tid];
        Wcs[tid] = Wc[tid];
    }
    __syncthreads();
    int row = blockIdx.x * 256 + tid;   // grid = 64 exact
    const float* zrow = z2 + (long)row * F2_;
    float acc = bc[0];
    #pragma unroll 4
    for (int k = 0; k < F2_; k += 4) {
        float4 x4 = *(const float4*)(zrow + k);
        float xs[4] = {x4.x, x4.y, x4.z, x4.w};
        #pragma unroll
        for (int u = 0; u < 4; u++) {
            int kk = k + u;
            float x = xs[u];
            float xn = x * Ab[kk] + Bb[kk];
            float p = sigmoidf_(xn);
            float al = alb[kk];
            float d = x * (al + p * (1.0f - al));
            acc += d * Wcs[kk];
        }
    }
    out[row] = sigmoidf_(acc);
}

extern "C" void kernel_launch(void* const* d_in, const int* in_sizes, int n_in,
                              void* d_out, int out_size, void* d_ws, size_t ws_size,
                              hipStream_t stream) {
    const int*   sparse = (const int*)  d_in[0];
    const int*   seqs   = (const int*)  d_in[1];
    const float* user_t = (const float*)d_in[2];
    const float* item_t = (const float*)d_in[3];
    const float* his_t  = (const float*)d_in[4];
    const float* W1  = (const float*)d_in[5];
    const float* b1  = (const float*)d_in[6];
    const float* g1  = (const float*)d_in[7];
    const float* be1 = (const float*)d_in[8];
    const float* a1  = (const float*)d_in[9];
    const float* W2  = (const float*)d_in[10];
    const float* b2  = (const float*)d_in[11];
    const float* Wf  = (const float*)d_in[12];
    const float* bfv = (const float*)d_in[13];
    const float* Wa  = (const float*)d_in[14];
    const float* ba  = (const float*)d_in[15];
    const float* ga  = (const float*)d_in[16];
    const float* bea = (const float*)d_in[17];
    const float* aa  = (const float*)d_in[18];
    const float* Wb  = (const float*)d_in[19];
    const float* bb  = (const float*)d_in[20];
    const float* gb  = (const float*)d_in[21];
    const float* beb = (const float*)d_in[22];
    const float* ab  = (const float*)d_in[23];
    const float* Wc  = (const float*)d_in[24];
    const float* bc  = (const float*)d_in[25];

    float* ws    = (float*)d_ws;
    float* score = ws + OFF_SCORE;
    float* cf    = ws + OFF_CF;
    float* acc   = ws + OFF_ACC;
    float* sum1  = acc;
    float* ssq1  = acc + 64;
    float* sumA  = acc + 128;
    float* ssqA  = acc + 328;
    float* sumB  = acc + 528;
    float* ssqB  = acc + 608;
    float* wv    = acc + 704;         // 65 floats: W2@Wf and c0 (not pre-zeroed)
    float* z1    = ws + OFF_Z1;
    float* z2    = ws + OFF_Z2;
    float* out   = (float*)d_out;
    // W1t (bf16 64x256 = 32 KB) aliases the score region: all blocks consume it
    // in gemm1 phase 1; score is written in phase 2, strictly after grid.sync.
    unsigned short* W1t = (unsigned short*)(ws + OFF_SCORE);

    k_init<<<64, 256, 0, stream>>>(acc, W1, W1t, W2, Wf, b2, bfv, wv);
    {
        void* args[] = {
            (void*)&sparse, (void*)&seqs, (void*)&item_t, (void*)&his_t,
            (void*)&W1t, (void*)&b1, (void*)&g1, (void*)&be1, (void*)&a1,
            (void*)&wv, (void*)&sum1, (void*)&ssq1, (void*)&score
        };
        hipLaunchCooperativeKernel(k_gemm1, dim3(640), dim3(256), args, 0, stream);
    }
    k_pool<<<B_ / 4, 256, 0, stream>>>(sparse, seqs, user_t, item_t, his_t, score, cf);
    k_z1<<<512, 256, 0, stream>>>(cf, Wa, ba, z1, sumA, ssqA);
    k_z2<<<512, 320, 0, stream>>>(z1, Wb, bb, sumA, ssqA, ga, bea, aa, z2, sumB, ssqB);
    k_out<<<B_ / 256, 256, 0, stream>>>(z2, sumB, ssqB, gb, beb, ab, Wc, bc, out);
}

// Round 2
// 758.146 us; speedup vs baseline: 1.1327x; 1.1327x over previous
//
#include <hip/hip_runtime.h>
#include <hip/hip_bf16.h>

// Problem constants (fixed by reference setup_inputs)
constexpr int B_   = 16384;
constexpr int L_   = 10;
constexpr int E_   = 64;
constexpr int BL_  = B_ * L_;       // 163840
constexpr int H1_  = 64;
constexpr int H2_  = 16;
constexpr int CF_  = 3 * E_;        // 192
constexpr int F1_  = 200;
constexpr int F2_  = 80;

// Workspace layout (in floats)
constexpr long OFF_T1    = 0;                       // BL*64 = 10485760
constexpr long OFF_SCORE = 10485760;                // BL (aliases W1t bf16 early)
constexpr long OFF_CF    = 10649600;                // B*192 -> ends 13795328
constexpr long OFF_ACC   = 13795328;                // 688 floats
constexpr long OFF_HISC  = 13796352;                // BL*64 = 10485760 -> ends 24282112
constexpr long OFF_Z1    = 0;                       // B*200 (aliases dead t1)
constexpr long OFF_Z2    = 3276800;                 // B*80
constexpr int  ACC_N     = 688;

typedef __bf16 bf16x8 __attribute__((ext_vector_type(8)));
typedef float  f32x4  __attribute__((ext_vector_type(4)));

__device__ __forceinline__ float sigmoidf_(float x) {
    return 1.0f / (1.0f + __expf(-x));
}

__device__ __forceinline__ unsigned short f2bf(float f) {
    unsigned u = __float_as_uint(f);
    unsigned r = (u + 0x7fffu + ((u >> 16) & 1u)) >> 16;   // RNE, values are finite
    return (unsigned short)r;
}
__device__ __forceinline__ unsigned pk2(float a, float b) {
    return (unsigned)f2bf(a) | ((unsigned)f2bf(b) << 16);
}

// ---------------- K0: zero accumulators + build W1t (bf16, transposed) -------
__global__ __launch_bounds__(256) void k_init(
    float* __restrict__ acc, const float* __restrict__ W1,
    unsigned short* __restrict__ W1t)
{
    int i = blockIdx.x * 256 + threadIdx.x;   // grid 64 -> i < 16384
    if (i < ACC_N) acc[i] = 0.0f;
    // W1 is [K=256][N=64] row-major f32; W1t is [N=64][K=256] bf16
    int k = i >> 6, n = i & 63;               // coalesced read of W1
    W1t[n * 256 + k] = f2bf(W1[i]);
}

// ---------------- K1: t1 = ai @ W1 + b1 via bf16 MFMA, + stats + hisc -------
// 1 tile (64 rows) per block, grid 2560.  As is XOR-swizzled (no pad):
// dword col c of row r stored at (c & ~31) + ((c & 31) ^ ((r & 7) << 2)).
// ds_read_b128 stays 16B-contiguous since the swizzle has no bits < 2.
// LDS = 32 KB exactly (reduction buffers union into As) -> 5 blocks/CU.
__global__ __launch_bounds__(256, 5) void k_gemm1(
    const int* __restrict__ sparse, const int* __restrict__ seqs,
    const float* __restrict__ item_t, const float* __restrict__ his_t,
    const unsigned short* __restrict__ W1t, const float* __restrict__ b1,
    float* __restrict__ t1, float* __restrict__ hisc,
    float* __restrict__ sum1, float* __restrict__ ssq1)
{
    __shared__ unsigned As[64 * 128];         // 32 KB

    int tid  = threadIdx.x;
    int lane = tid & 63;
    int wave = tid >> 6;
    int m    = lane & 15;
    int quad = (lane >> 4) & 3;
    int colg = 16 * wave + m;                 // this lane's output column

    // B fragments: b_frag[kk][j] = W1t[colg][kk*32 + quad*8 + j]
    bf16x8 bfr[8];
    {
        const unsigned short* wp = W1t + (long)colg * 256 + quad * 8;
        #pragma unroll
        for (int kk = 0; kk < 8; kk++)
            bfr[kk] = *(const bf16x8*)(wp + kk * 32);
    }
    float bias = b1[colg];
    int row0 = blockIdx.x * 64;               // grid 2560 exact

    // stage ai tile: 64 rows x 32 bf16-pairs, 4 segments (q,h,q-h,q*h)
    #pragma unroll 4
    for (int t = 0; t < 8; t++) {
        int slot = t * 256 + tid;             // 0..2047
        int p = slot & 31;                    // pair index (cols 2p,2p+1)
        int r = slot >> 5;                    // row within tile
        int row = row0 + r;
        int b = (unsigned)row / 10u;
        int item = sparse[2 * b + 1];
        int hidx = seqs[row];
        float2 q2 = *(const float2*)(item_t + (long)item * 64 + 2 * p);
        float2 h2 = *(const float2*)(his_t  + (long)hidx * 64 + 2 * p);
        *(float2*)(hisc + (long)row * 64 + 2 * p) = h2;   // contiguous his cache
        unsigned sw = (unsigned)(r & 7) << 2;
        unsigned* a = &As[r * 128];
        unsigned ps_ = p ^ sw;
        a[ps_]      = pk2(q2.x, q2.y);
        a[32 + ps_] = pk2(h2.x, h2.y);
        a[64 + ps_] = pk2(q2.x - h2.x, q2.y - h2.y);
        a[96 + ps_] = pk2(q2.x * h2.x, q2.y * h2.y);
    }
    __syncthreads();

    f32x4 acc[4] = {{0,0,0,0},{0,0,0,0},{0,0,0,0},{0,0,0,0}};
    unsigned swm = (unsigned)(m & 7) << 2;    // same for rows m, 16+m, 32+m, 48+m
    #pragma unroll
    for (int kk = 0; kk < 8; kk++) {
        unsigned aoff = (unsigned)(kk * 16 + quad * 4);
        unsigned c = (aoff & ~31u) + ((aoff & 31u) ^ swm);
        bf16x8 a0 = *(const bf16x8*)&As[( 0 + m) * 128 + c];
        bf16x8 a1 = *(const bf16x8*)&As[(16 + m) * 128 + c];
        bf16x8 a2 = *(const bf16x8*)&As[(32 + m) * 128 + c];
        bf16x8 a3 = *(const bf16x8*)&As[(48 + m) * 128 + c];
        acc[0] = __builtin_amdgcn_mfma_f32_16x16x32_bf16(a0, bfr[kk], acc[0], 0, 0, 0);
        acc[1] = __builtin_amdgcn_mfma_f32_16x16x32_bf16(a1, bfr[kk], acc[1], 0, 0, 0);
        acc[2] = __builtin_amdgcn_mfma_f32_16x16x32_bf16(a2, bfr[kk], acc[2], 0, 0, 0);
        acc[3] = __builtin_amdgcn_mfma_f32_16x16x32_bf16(a3, bfr[kk], acc[3], 0, 0, 0);
    }
    // epilogue: D row = 16*rs + quad*4 + reg, col = colg
    float ps = 0.0f, pq = 0.0f;
    float* tb = t1 + (long)row0 * 64 + colg;
    #pragma unroll
    for (int rs = 0; rs < 4; rs++) {
        #pragma unroll
        for (int reg = 0; reg < 4; reg++) {
            float v = acc[rs][reg] + bias;
            tb[(16 * rs + quad * 4 + reg) * 64] = v;
            ps += v; pq += v * v;
        }
    }

    __syncthreads();                          // As dead; reuse as reduction buf
    float* red = (float*)As;
    red[quad * 64 + colg]       = ps;
    red[256 + quad * 64 + colg] = pq;
    __syncthreads();
    if (tid < 64) {
        float s = red[tid] + red[64 + tid] + red[128 + tid] + red[192 + tid];
        float q = red[256 + tid] + red[320 + tid] + red[384 + tid] + red[448 + tid];
        atomicAdd(&sum1[tid], s);
        atomicAdd(&ssq1[tid], q);
    }
}

// ---------------- K2: score = (dice3(t1) @ W2 + b2) @ Wf + bf, masked --------
__global__ __launch_bounds__(256) void k_score(
    const float* __restrict__ t1, const int* __restrict__ seqs,
    const float* __restrict__ sum1, const float* __restrict__ ssq1,
    const float* __restrict__ g1, const float* __restrict__ be1, const float* __restrict__ a1v,
    const float* __restrict__ W2, const float* __restrict__ b2,
    const float* __restrict__ Wf, const float* __restrict__ bfv,
    float* __restrict__ score)
{
    __shared__ float As[64], Bs[64], Al[64];
    __shared__ float W2s[64 * 16];
    __shared__ float Wfs[16], b2s[16];
    int tid = threadIdx.x;
    if (tid < 64) {
        float mu = sum1[tid] * (1.0f / BL_);
        float var = ssq1[tid] * (1.0f / BL_) - mu * mu;
        float rstd = rsqrtf(var + 1e-8f);
        float A = rstd * g1[tid];
        As[tid] = A;
        Bs[tid] = be1[tid] - mu * A;
        Al[tid] = a1v[tid];
    }
    for (int i = tid; i < 64 * 16; i += 256) W2s[i] = W2[i];
    if (tid < 16) { Wfs[tid] = Wf[tid]; b2s[tid] = b2[tid]; }
    __syncthreads();

    int row = blockIdx.x * 256 + tid;   // grid = 640 exact
    float h[16];
    #pragma unroll
    for (int n = 0; n < 16; n++) h[n] = b2s[n];
    const float* trow = t1 + (long)row * 64;
    #pragma unroll 4
    for (int jj = 0; jj < 64; jj += 4) {
        float4 x4 = *(const float4*)(trow + jj);
        float xs[4] = {x4.x, x4.y, x4.z, x4.w};
        #pragma unroll
        for (int u = 0; u < 4; u++) {
            int j = jj + u;
            float x = xs[u];
            float xn = x * As[j] + Bs[j];
            float p = sigmoidf_(xn);
            float al = Al[j];
            float d = x * (al + p * (1.0f - al));
            #pragma unroll
            for (int n = 0; n < 16; n++) h[n] += d * W2s[j * 16 + n];
        }
    }
    float sc = bfv[0];
    #pragma unroll
    for (int n = 0; n < 16; n++) sc += h[n] * Wfs[n];
    if (seqs[row] == 0) sc = 0.0f;
    score[row] = sc;
}

// ---------------- K2b: pooled + cf assembly (hisc is contiguous now) ---------
__global__ __launch_bounds__(256) void k_pool(
    const int* __restrict__ sparse,
    const float* __restrict__ user_t, const float* __restrict__ item_t,
    const float* __restrict__ hisc,
    const float* __restrict__ score, float* __restrict__ cf)
{
    int tid = threadIdx.x;
    int b = blockIdx.x * 4 + (tid >> 6);   // grid = 4096 exact
    int e = tid & 63;
    float acc = 0.0f;
    #pragma unroll
    for (int l = 0; l < L_; l++) {
        float s = score[b * L_ + l];
        acc += s * hisc[(long)(b * L_ + l) * 64 + e];
    }
    int uidx = sparse[2 * b];
    int iidx = sparse[2 * b + 1];
    cf[(long)b * CF_ + e]        = item_t[(long)iidx * 64 + e];
    cf[(long)b * CF_ + 64 + e]   = acc;
    cf[(long)b * CF_ + 128 + e]  = user_t[(long)uidx * 64 + e];
}

// ---------------- K3: z1 = cf @ Wa + ba, register-blocked 8 rows x 4 cols ----
// Tile: 32 rows x 200 cols, 1 tile/block, grid 512.  Thread t<200:
// rh = t/50 -> rows 8rh..8rh+7, cp = t%50 -> cols 4cp..4cp+3.
// LDS ds_read_b128 per thread-tile: 48*8 = 384 (was 768 over a 16-row tile).
__global__ __launch_bounds__(256) void k_z1(
    const float* __restrict__ cf, const float* __restrict__ Wa, const float* __restrict__ ba,
    float* __restrict__ z1, float* __restrict__ sumA, float* __restrict__ ssqA)
{
    __shared__ float cfs[32 * CF_];   // 24 KB
    int tid = threadIdx.x;
    int row0 = blockIdx.x * 32;       // grid 512 exact

    for (int i = tid; i < 32 * CF_ / 4; i += 256)
        ((float4*)cfs)[i] = ((const float4*)(cf + (long)row0 * CF_))[i];
    __syncthreads();

    float4 accv[8];
    int cp = tid % 50, rh = tid / 50;         // rh < 4 when tid < 200
    float psj[4] = {0,0,0,0}, pqj[4] = {0,0,0,0};
    if (tid < 200) {
        #pragma unroll
        for (int r = 0; r < 8; r++) accv[r] = make_float4(0.f, 0.f, 0.f, 0.f);
        for (int kk = 0; kk < CF_ / 4; kk++) {
            float4 w0 = *(const float4*)(Wa + (long)(4 * kk + 0) * F1_ + 4 * cp);
            float4 w1 = *(const float4*)(Wa + (long)(4 * kk + 1) * F1_ + 4 * cp);
            float4 w2 = *(const float4*)(Wa + (long)(4 * kk + 2) * F1_ + 4 * cp);
            float4 w3 = *(const float4*)(Wa + (long)(4 * kk + 3) * F1_ + 4 * cp);
            #pragma unroll
            for (int r = 0; r < 8; r++) {
                float4 c = *(const float4*)&cfs[(8 * rh + r) * CF_ + 4 * kk];
                accv[r].x += c.x * w0.x + c.y * w1.x + c.z * w2.x + c.w * w3.x;
                accv[r].y += c.x * w0.y + c.y * w1.y + c.z * w2.y + c.w * w3.y;
                accv[r].z += c.x * w0.z + c.y * w1.z + c.z * w2.z + c.w * w3.z;
                accv[r].w += c.x * w0.w + c.y * w1.w + c.z * w2.w + c.w * w3.w;
            }
        }
        float4 bav = *(const float4*)(ba + 4 * cp);
        #pragma unroll
        for (int r = 0; r < 8; r++) {
            float4 v = make_float4(accv[r].x + bav.x, accv[r].y + bav.y,
                                   accv[r].z + bav.z, accv[r].w + bav.w);
            *(float4*)(z1 + (long)(row0 + 8 * rh + r) * F1_ + 4 * cp) = v;
            psj[0] += v.x; pqj[0] += v.x * v.x;
            psj[1] += v.y; pqj[1] += v.y * v.y;
            psj[2] += v.z; pqj[2] += v.z * v.z;
            psj[3] += v.w; pqj[3] += v.w * v.w;
        }
    }
    __syncthreads();                   // cfs dead; reuse for stat reduction
    if (tid < 200) {
        #pragma unroll
        for (int j = 0; j < 4; j++) {
            cfs[rh * 200 + 4 * cp + j]       = psj[j];
            cfs[800 + rh * 200 + 4 * cp + j] = pqj[j];
        }
    }
    __syncthreads();
    if (tid < F1_) {
        float s = cfs[tid] + cfs[200 + tid] + cfs[400 + tid] + cfs[600 + tid];
        float q = cfs[800 + tid] + cfs[1000 + tid] + cfs[1200 + tid] + cfs[1400 + tid];
        atomicAdd(&sumA[tid], s);
        atomicAdd(&ssqA[tid], q);
    }
}

// ---------------- K4: z2 = dice2(z1) @ Wb + bb, plus sums --------------------
__global__ __launch_bounds__(320) void k_z2(
    const float* __restrict__ z1, const float* __restrict__ Wb, const float* __restrict__ bbv,
    const float* __restrict__ sumA, const float* __restrict__ ssqA,
    const float* __restrict__ ga, const float* __restrict__ bea, const float* __restrict__ aav,
    float* __restrict__ z2, float* __restrict__ sumB, float* __restrict__ ssqB)
{
    __shared__ float zs[16 * F1_];    // 12.8 KB
    __shared__ float Aa[F1_], Ba[F1_], ala[F1_];
    int tid = threadIdx.x;
    if (tid < F1_) {
        float mu = sumA[tid] * (1.0f / B_);
        float var = ssqA[tid] * (1.0f / B_) - mu * mu;
        float rstd = rsqrtf(var + 1e-8f);
        float A = rstd * ga[tid];
        Aa[tid] = A;
        Ba[tid] = bea[tid] - mu * A;
        ala[tid] = aav[tid];
    }
    int n = tid % F2_;       // 0..79
    int rgrp = tid / F2_;    // 0..3
    float bbl = bbv[n];
    float ps = 0.f, pq = 0.f;

    int ntile = B_ / 16;   // 1024
    for (int tile = blockIdx.x; tile < ntile; tile += gridDim.x) {
        int row0 = tile * 16;
        __syncthreads();
        for (int i = tid; i < 16 * F1_; i += 320) {
            int k = i % F1_;
            float x = z1[(long)row0 * F1_ + i];
            float xn = x * Aa[k] + Ba[k];
            float p = sigmoidf_(xn);
            float al = ala[k];
            zs[i] = x * (al + p * (1.0f - al));
        }
        __syncthreads();
        float acc[4] = {0.f, 0.f, 0.f, 0.f};
        for (int k = 0; k < F1_; k += 4) {
            float w0 = Wb[(long)(k + 0) * F2_ + n];
            float w1 = Wb[(long)(k + 1) * F2_ + n];
            float w2 = Wb[(long)(k + 2) * F2_ + n];
            float w3 = Wb[(long)(k + 3) * F2_ + n];
            #pragma unroll
            for (int rr = 0; rr < 4; rr++) {
                float4 c4 = *(const float4*)&zs[(rgrp * 4 + rr) * F1_ + k];
                acc[rr] += c4.x * w0 + c4.y * w1 + c4.z * w2 + c4.w * w3;
            }
        }
        #pragma unroll
        for (int rr = 0; rr < 4; rr++) {
            int row = row0 + rgrp * 4 + rr;
            float v = acc[rr] + bbl;
            z2[(long)row * F2_ + n] = v;
            ps += v; pq += v * v;
        }
    }
    atomicAdd(&sumB[n], ps);
    atomicAdd(&ssqB[n], pq);
}

// ---------------- K5: out = sigmoid(dice2(z2) @ Wc + bc) ---------------------
__global__ __launch_bounds__(256) void k_out(
    const float* __restrict__ z2,
    const float* __restrict__ sumB, const float* __restrict__ ssqB,
    const float* __restrict__ gb, const float* __restrict__ beb, const float* __restrict__ abv,
    const float* __restrict__ Wc, const float* __restrict__ bc,
    float* __restrict__ out)
{
    __shared__ float Ab[F2_], Bb[F2_], alb[F2_], Wcs[F2_];
    int tid = threadIdx.x;
    if (tid < F2_) {
        float mu = sumB[tid] * (1.0f / B_);
        float var = ssqB[tid] * (1.0f / B_) - mu * mu;
        float rstd = rsqrtf(var + 1e-8f);
        float A = rstd * gb[tid];
        Ab[tid] = A;
        Bb[tid] = beb[tid] - mu * A;
        alb[tid] = abv[tid];
        Wcs[tid] = Wc[tid];
    }
    __syncthreads();
    int row = blockIdx.x * 256 + tid;   // grid = 64 exact
    const float* zrow = z2 + (long)row * F2_;
    float acc = bc[0];
    #pragma unroll 4
    for (int k = 0; k < F2_; k += 4) {
        float4 x4 = *(const float4*)(zrow + k);
        float xs[4] = {x4.x, x4.y, x4.z, x4.w};
        #pragma unroll
        for (int u = 0; u < 4; u++) {
            int kk = k + u;
            float x = xs[u];
            float xn = x * Ab[kk] + Bb[kk];
            float p = sigmoidf_(xn);
            float al = alb[kk];
            float d = x * (al + p * (1.0f - al));
            acc += d * Wcs[kk];
        }
    }
    out[row] = sigmoidf_(acc);
}

extern "C" void kernel_launch(void* const* d_in, const int* in_sizes, int n_in,
                              void* d_out, int out_size, void* d_ws, size_t ws_size,
                              hipStream_t stream) {
    const int*   sparse = (const int*)  d_in[0];
    const int*   seqs   = (const int*)  d_in[1];
    const float* user_t = (const float*)d_in[2];
    const float* item_t = (const float*)d_in[3];
    const float* his_t  = (const float*)d_in[4];
    const float* W1  = (const float*)d_in[5];
    const float* b1  = (const float*)d_in[6];
    const float* g1  = (const float*)d_in[7];
    const float* be1 = (const float*)d_in[8];
    const float* a1  = (const float*)d_in[9];
    const float* W2  = (const float*)d_in[10];
    const float* b2  = (const float*)d_in[11];
    const float* Wf  = (const float*)d_in[12];
    const float* bfv = (const float*)d_in[13];
    const float* Wa  = (const float*)d_in[14];
    const float* ba  = (const float*)d_in[15];
    const float* ga  = (const float*)d_in[16];
    const float* bea = (const float*)d_in[17];
    const float* aa  = (const float*)d_in[18];
    const float* Wb  = (const float*)d_in[19];
    const float* bb  = (const float*)d_in[20];
    const float* gb  = (const float*)d_in[21];
    const float* beb = (const float*)d_in[22];
    const float* ab  = (const float*)d_in[23];
    const float* Wc  = (const float*)d_in[24];
    const float* bc  = (const float*)d_in[25];

    float* ws    = (float*)d_ws;
    float* t1    = ws + OFF_T1;
    float* score = ws + OFF_SCORE;
    float* cf    = ws + OFF_CF;
    float* acc   = ws + OFF_ACC;
    float* hisc  = ws + OFF_HISC;
    float* sum1  = acc;
    float* ssq1  = acc + 64;
    float* sumA  = acc + 128;
    float* ssqA  = acc + 328;
    float* sumB  = acc + 528;
    float* ssqB  = acc + 608;
    float* z1    = ws + OFF_Z1;
    float* z2    = ws + OFF_Z2;
    float* out   = (float*)d_out;
    // W1t (bf16 64x256 = 32 KB) aliases the score region: dead before k_score writes it
    unsigned short* W1t = (unsigned short*)(ws + OFF_SCORE);

    k_init<<<64, 256, 0, stream>>>(acc, W1, W1t);
    k_gemm1<<<BL_ / 64, 256, 0, stream>>>(sparse, seqs, item_t, his_t, W1t, b1, t1, hisc, sum1, ssq1);
    k_score<<<BL_ / 256, 256, 0, stream>>>(t1, seqs, sum1, ssq1, g1, be1, a1, W2, b2, Wf, bfv, score);
    k_pool<<<B_ / 4, 256, 0, stream>>>(sparse, user_t, item_t, hisc, score, cf);
    k_z1<<<B_ / 32, 256, 0, stream>>>(cf, Wa, ba, z1, sumA, ssqA);
    k_z2<<<512, 320, 0, stream>>>(z1, Wb, bb, sumA, ssqA, ga, bea, aa, z2, sumB, ssqB);
    k_out<<<B_ / 256, 256, 0, stream>>>(z2, sumB, ssqB, gb, beb, ab, Wc, bc, out);
}